// Round 6
// baseline (201.497 us; speedup 1.0000x reference)
//
#include <hip/hip_runtime.h>
#include <hip/hip_cooperative_groups.h>
#include <math.h>

namespace cg = cooperative_groups;

#define NNODES 20000
#define NEDGES 640000
#define C 128

// one cooperative launch: 64 blocks x 1024 threads (trivially co-resident on 256 CUs)
#define NB 64
#define BT 1024
#define EPT 10   // edges per thread: ceil(640000 / 65536)

// packed per-edge LDS atomic: bits[26,32)=count, bits[0,26)=fix16 sum biased 2^19/edge
// per-(block,node) count <= ~10 << 63; sum field <= ~10 * 2^20 << 2^26. Proven R5.
#define CNT_SHIFT 26
#define EDGE_BIAS (1 << 19)
#define SUM_MASK 0x03FFFFFFu

__global__ void __launch_bounds__(BT)
k_all(const float* __restrict__ x,
      const int* __restrict__ ei, const float* __restrict__ attr,
      const float* __restrict__ g_w, const float* __restrict__ g_b,
      const float* __restrict__ f_w, const float* __restrict__ f_b,
      const float* __restrict__ cls_w, const float* __restrict__ cls_b,
      float* __restrict__ xu, float* __restrict__ xp, float* __restrict__ r,
      unsigned int* __restrict__ part, float* __restrict__ out)
{
    __shared__ unsigned int lacc[NNODES];                 // 80 KB node table
    __shared__ float csh[C], vsh[C], ush[C], psh[C], qsh[C];
    __shared__ float red[BT];
    __shared__ float sgbv, sgev, sc0;

    cg::grid_group grid = cg::this_grid();
    const int tid  = threadIdx.x;
    const int gtid = blockIdx.x * BT + tid;

    // ---- early-issue edge loads; consumed in phase C, overlap phases A/B ----
    int   esrc[EPT];
    int   edst[EPT];
    float eatt[EPT];
    #pragma unroll
    for (int i = 0; i < EPT; ++i) {
        int e = gtid + i * (NB * BT);
        bool ok = (e < NEDGES);
        esrc[i] = ok ? ei[e] : 0;            // edge_index[0] = src
        edst[i] = ok ? ei[NEDGES + e] : -1;  // edge_index[1] = dst (-1 = skip)
        eatt[i] = ok ? attr[e] : 0.f;
    }

    // ---- phase A: weight collapse, redundant per block (identical barrier
    //      sequence in every block — no R4-style grid divergence) ----------
    //   u[k]=f_w[k,:].cls  v[k]=f_w[128+k,:].cls  p[k]=g_w[k,:].v  q[k]=g_w[128+k,:].v
    //   gbv=g_b.v  gev=g_w[256,:].v  c0=f_b.cls + cls_b
    {
        int pair = tid >> 2;      // 0..255
        int prt  = tid & 3;       // 32-channel segment
        int k = pair & 127;
        int h = pair >> 7;

        if (tid < C) csh[tid] = cls_w[tid];
        __syncthreads();

        const float4* fw4 = (const float4*)f_w;
        const float4* gw4 = (const float4*)g_w;
        const float4* cs4 = (const float4*)csh;

        {   // u (h=0) / v (h=1)
            const float4* row = fw4 + (size_t)(h * C + k) * (C / 4) + prt * 8;
            const float4* cc  = cs4 + prt * 8;
            float s = 0.f;
            #pragma unroll
            for (int j = 0; j < 8; ++j) {
                float4 a = row[j], c = cc[j];
                s += a.x * c.x + a.y * c.y + a.z * c.z + a.w * c.w;
            }
            red[tid] = s;
        }
        __syncthreads();
        if (prt == 0) {
            float tot = red[tid] + red[tid + 1] + red[tid + 2] + red[tid + 3];
            if (h == 0) ush[k] = tot; else vsh[k] = tot;
        }
        __syncthreads();

        const float4* vs4 = (const float4*)vsh;
        {   // p (h=0) / q (h=1)
            const float4* row = gw4 + (size_t)(h * C + k) * (C / 4) + prt * 8;
            const float4* vv  = vs4 + prt * 8;
            float s = 0.f;
            #pragma unroll
            for (int j = 0; j < 8; ++j) {
                float4 a = row[j], c = vv[j];
                s += a.x * c.x + a.y * c.y + a.z * c.z + a.w * c.w;
            }
            red[tid] = s;
        }
        __syncthreads();
        if (prt == 0) {
            float tot = red[tid] + red[tid + 1] + red[tid + 2] + red[tid + 3];
            if (h == 0) psh[k] = tot; else qsh[k] = tot;
        }
        __syncthreads();

        // three 128-length scalar dots via LDS tree
        if (tid < C) red[tid] = g_b[tid] * vsh[tid];
        __syncthreads();
        for (int s = 64; s > 0; s >>= 1) { if (tid < s) red[tid] += red[tid + s]; __syncthreads(); }
        if (tid == 0) sgbv = red[0];
        __syncthreads();
        if (tid < C) red[tid] = g_w[256 * C + tid] * vsh[tid];
        __syncthreads();
        for (int s = 64; s > 0; s >>= 1) { if (tid < s) red[tid] += red[tid + s]; __syncthreads(); }
        if (tid == 0) sgev = red[0];
        __syncthreads();
        if (tid < C) red[tid] = f_b[tid] * csh[tid];
        __syncthreads();
        for (int s = 64; s > 0; s >>= 1) { if (tid < s) red[tid] += red[tid + s]; __syncthreads(); }
        if (tid == 0) sc0 = red[0] + cls_b[0];
        __syncthreads();
    }

    // ---- phase B: zero LDS table + wave-per-node dots ----------------------
    uint4* l4 = (uint4*)lacc;
    for (int i = tid; i < NNODES / 4; i += BT) l4[i] = make_uint4(0u, 0u, 0u, 0u);

    {
        int w = tid >> 6, lane = tid & 63;
        int gwave = blockIdx.x * (BT / 64) + w;    // 0..1023
        float2 uu = ((const float2*)ush)[lane];
        float2 pp = ((const float2*)psh)[lane];
        float2 qq = ((const float2*)qsh)[lane];

        for (int n = gwave; n < NNODES; n += NB * (BT / 64)) {
            float2 xx = ((const float2*)(x + (size_t)n * C))[lane];
            float du = xx.x * uu.x + xx.y * uu.y;
            float dp = xx.x * pp.x + xx.y * pp.y;
            float dq = xx.x * qq.x + xx.y * qq.y;
            for (int off = 32; off > 0; off >>= 1) {
                du += __shfl_down(du, off);
                dp += __shfl_down(dp, off);
                dq += __shfl_down(dq, off);
            }
            if (lane == 0) { xu[n] = du; xp[n] = dp; r[n] = dq; }
        }
    }

    __threadfence();   // make r visible device-wide (cross-XCD)
    grid.sync();

    // ---- phase C: per-edge scatter (LDS atomics) + coalesced flush ---------
    {
        float gev = sgev;
        #pragma unroll
        for (int i = 0; i < EPT; ++i) {
            int d = edst[i];
            if (d >= 0) {
                float t = r[esrc[i]] + eatt[i] * gev;
                int fix = __float2int_rn(t * 65536.0f);
                atomicAdd(&lacc[d], (1u << CNT_SHIFT) + (unsigned int)(fix + EDGE_BIAS));
            }
        }
    }
    __syncthreads();

    {
        uint4* mp4 = (uint4*)(part + (size_t)blockIdx.x * NNODES);
        for (int i = tid; i < NNODES / 4; i += BT) mp4[i] = l4[i];
    }

    __threadfence();   // make part visible device-wide
    grid.sync();

    // ---- phase D: merge 64 partials + finalize -----------------------------
    // block b handles contiguous nodes [b*313, b*313+313) -> coalesced reads,
    // all 64 blocks busy (313 active threads each).
    {
        int n = blockIdx.x * 313 + tid;
        if (tid < 313 && n < NNODES) {
            int sumfix = 0, cnt = 0;
            #pragma unroll 8
            for (int b = 0; b < NB; ++b) {
                unsigned int v = part[(size_t)b * NNODES + n];
                int c = (int)(v >> CNT_SHIFT);
                cnt += c;
                sumfix += (int)(v & SUM_MASK) - (c << 19);
            }
            float sacc = (float)sumfix * (1.0f / 65536.0f);
            float cmax = fmaxf((float)cnt, 1.0f);
            float cfac = (cnt > 0) ? 1.0f : 0.0f;
            float logit = xu[n] + cfac * (xp[n] + sgbv) + sacc / cmax + sc0;
            float pr = 1.0f / (1.0f + expf(-logit));
            out[n] = (pr > 0.5f) ? 1.0f : 0.0f;
            out[NNODES + n] = pr;
        }
    }
}

extern "C" void kernel_launch(void* const* d_in, const int* in_sizes, int n_in,
                              void* d_out, int out_size, void* d_ws, size_t ws_size,
                              hipStream_t stream) {
    const float* x_a       = (const float*)d_in[0];
    const int*   ei        = (const int*)d_in[1];    // [2, E]
    const float* edge_attr = (const float*)d_in[2];  // [E, 1]
    const float* g_w       = (const float*)d_in[3];  // [257,128]
    const float* g_b       = (const float*)d_in[4];  // [128]
    const float* f_w       = (const float*)d_in[5];  // [256,128]
    const float* f_b       = (const float*)d_in[6];  // [128]
    const float* cls_w     = (const float*)d_in[7];  // [128,1]
    const float* cls_b     = (const float*)d_in[8];  // [1]
    float* out = (float*)d_out;

    // workspace layout: part first (16B-aligned), then node scalars
    unsigned int* part = (unsigned int*)d_ws;                  // NB*N u32 = 5.12 MB
    float* xu = (float*)d_ws + (size_t)NB * NNODES;            // N
    float* xp = xu + NNODES;                                   // N
    float* r  = xp + NNODES;                                   // N

    void* args[] = {
        (void*)&x_a, (void*)&ei, (void*)&edge_attr,
        (void*)&g_w, (void*)&g_b, (void*)&f_w, (void*)&f_b,
        (void*)&cls_w, (void*)&cls_b,
        (void*)&xu, (void*)&xp, (void*)&r, (void*)&part, (void*)&out
    };
    hipLaunchCooperativeKernel((const void*)k_all, dim3(NB), dim3(BT),
                               args, 0, stream);
}

// Round 7
// 104.947 us; speedup vs baseline: 1.9200x; 1.9200x over previous
//
#include <hip/hip_runtime.h>
#include <math.h>

#define NNODES 20000
#define NEDGES 640000
#define C 128

// k_edge: 128 blocks x 1024 threads, 80 KB LDS (1 block/CU)
#define NB 128
#define BT 1024

// packed per-edge LDS atomic: bits[26,32)=count, bits[0,26)=fix16 sum biased 2^19/edge
// per-(block,node) count mean 0.25, max ~10 << 63; per-edge term < 2^20, sum << 2^26.
#define CNT_SHIFT 26
#define EDGE_BIAS (1 << 19)
#define SUM_MASK 0x03FFFFFFu

// ---------------------------------------------------------------------------
// K1: fused weight-collapse + per-node dots. 256 blocks x 1024 threads.
// Phase A is R6's correctness-verified code: EVERY block redundantly collapses
// the layers into LDS (identical instruction/barrier sequence in all blocks —
// no block-divergent reductions), and every block stores the bit-identical
// scal[] values (benign same-value stores). Phase B: wave-per-node dots.
//   u[k]=f_w[k,:].cls  v[k]=f_w[128+k,:].cls  p[k]=g_w[k,:].v  q[k]=g_w[128+k,:].v
//   scal={g_b.v, g_w[256,:].v, f_b.cls+cls_b}
//   xu[n]=x[n].u  xp[n]=x[n].p  r[n]=x[n].q
// ---------------------------------------------------------------------------
__global__ void __launch_bounds__(BT)
k_node(const float* __restrict__ x,
       const float* __restrict__ g_w, const float* __restrict__ g_b,
       const float* __restrict__ f_w, const float* __restrict__ f_b,
       const float* __restrict__ cls_w, const float* __restrict__ cls_b,
       float* __restrict__ xu, float* __restrict__ xp,
       float* __restrict__ r, float* __restrict__ scal)
{
    __shared__ float csh[C], vsh[C], ush[C], psh[C], qsh[C];
    __shared__ float red[BT];
    const int tid = threadIdx.x;

    // ---- phase A (verified in R6) ----
    {
        int pair = tid >> 2;      // 0..255 : (k,h)
        int prt  = tid & 3;       // 32-channel segment
        int k = pair & 127;
        int h = pair >> 7;

        if (tid < C) csh[tid] = cls_w[tid];
        __syncthreads();

        const float4* fw4 = (const float4*)f_w;
        const float4* gw4 = (const float4*)g_w;
        const float4* cs4 = (const float4*)csh;

        {   // u (h=0) / v (h=1)
            const float4* row = fw4 + (size_t)(h * C + k) * (C / 4) + prt * 8;
            const float4* cc  = cs4 + prt * 8;
            float s = 0.f;
            #pragma unroll
            for (int j = 0; j < 8; ++j) {
                float4 a = row[j], c = cc[j];
                s += a.x * c.x + a.y * c.y + a.z * c.z + a.w * c.w;
            }
            red[tid] = s;
        }
        __syncthreads();
        if (prt == 0) {
            float tot = red[tid] + red[tid + 1] + red[tid + 2] + red[tid + 3];
            if (h == 0) ush[k] = tot; else vsh[k] = tot;
        }
        __syncthreads();

        const float4* vs4 = (const float4*)vsh;
        {   // p (h=0) / q (h=1)
            const float4* row = gw4 + (size_t)(h * C + k) * (C / 4) + prt * 8;
            const float4* vv  = vs4 + prt * 8;
            float s = 0.f;
            #pragma unroll
            for (int j = 0; j < 8; ++j) {
                float4 a = row[j], c = vv[j];
                s += a.x * c.x + a.y * c.y + a.z * c.z + a.w * c.w;
            }
            red[tid] = s;
        }
        __syncthreads();
        if (prt == 0) {
            float tot = red[tid] + red[tid + 1] + red[tid + 2] + red[tid + 3];
            if (h == 0) psh[k] = tot; else qsh[k] = tot;
        }
        __syncthreads();   // separates red reads above from red overwrite below

        // three 128-length scalar dots via LDS tree (all blocks, identical)
        if (tid < C) red[tid] = g_b[tid] * vsh[tid];
        __syncthreads();
        for (int s = 64; s > 0; s >>= 1) { if (tid < s) red[tid] += red[tid + s]; __syncthreads(); }
        if (tid == 0) scal[0] = red[0];
        __syncthreads();
        if (tid < C) red[tid] = g_w[256 * C + tid] * vsh[tid];
        __syncthreads();
        for (int s = 64; s > 0; s >>= 1) { if (tid < s) red[tid] += red[tid + s]; __syncthreads(); }
        if (tid == 0) scal[1] = red[0];
        __syncthreads();
        if (tid < C) red[tid] = f_b[tid] * csh[tid];
        __syncthreads();
        for (int s = 64; s > 0; s >>= 1) { if (tid < s) red[tid] += red[tid + s]; __syncthreads(); }
        if (tid == 0) scal[2] = red[0] + cls_b[0];
        __syncthreads();
    }

    // ---- phase B: wave-per-node dots ----
    {
        int w = tid >> 6, lane = tid & 63;
        int gwave = blockIdx.x * (BT / 64) + w;        // 0..4095
        float2 uu = ((const float2*)ush)[lane];
        float2 pp = ((const float2*)psh)[lane];
        float2 qq = ((const float2*)qsh)[lane];

        for (int n = gwave; n < NNODES; n += 256 * (BT / 64)) {
            float2 xx = ((const float2*)(x + (size_t)n * C))[lane];
            float du = xx.x * uu.x + xx.y * uu.y;
            float dp = xx.x * pp.x + xx.y * pp.y;
            float dq = xx.x * qq.x + xx.y * qq.y;
            for (int off = 32; off > 0; off >>= 1) {
                du += __shfl_down(du, off);
                dp += __shfl_down(dp, off);
                dq += __shfl_down(dq, off);
            }
            if (lane == 0) { xu[n] = du; xp[n] = dp; r[n] = dq; }
        }
    }
}

// ---------------------------------------------------------------------------
// K2: per-edge scatter (R5-verified code, NB=128). Full 20000-entry u32 table
// in LDS (80 KB), ONE LDS atomic per edge, uint4 coalesced flush.
// ---------------------------------------------------------------------------
__global__ void __launch_bounds__(BT)
k_edge(const int* __restrict__ ei, const float* __restrict__ attr,
       const float* __restrict__ r, const float* __restrict__ scal,
       unsigned int* __restrict__ part)
{
    __shared__ unsigned int lacc[NNODES];
    int tid = threadIdx.x;

    uint4* l4 = (uint4*)lacc;
    for (int i = tid; i < NNODES / 4; i += BT) l4[i] = make_uint4(0u, 0u, 0u, 0u);
    __syncthreads();

    float gev = scal[1];
    for (int e = blockIdx.x * BT + tid; e < NEDGES; e += NB * BT) {
        int s = ei[e];            // src
        int d = ei[NEDGES + e];   // dst
        float t = r[s] + attr[e] * gev;
        int fix = __float2int_rn(t * 65536.0f);
        atomicAdd(&lacc[d], (1u << CNT_SHIFT) + (unsigned int)(fix + EDGE_BIAS));
    }
    __syncthreads();

    uint4* mp4 = (uint4*)(part + (size_t)blockIdx.x * NNODES);
    for (int i = tid; i < NNODES / 4; i += BT) mp4[i] = l4[i];
}

// ---------------------------------------------------------------------------
// K3: merge NB partials per node — quad-per-node: 4 consecutive lanes each
// merge NB/4 partials, combined by two intra-wave __shfl_down steps (no LDS,
// wave-synchronous). 313 blocks x 256 threads keep all the read BW busy.
// ---------------------------------------------------------------------------
__global__ void __launch_bounds__(256)
k_final(const float* __restrict__ xu, const float* __restrict__ xp,
        const unsigned int* __restrict__ part,
        const float* __restrict__ scal, float* __restrict__ out)
{
    int t = threadIdx.x;
    int quad = t >> 2;                 // 0..63
    int prt  = t & 3;
    int n = blockIdx.x * 64 + quad;

    int sumfix = 0, cnt = 0;
    if (n < NNODES) {
        const unsigned int* pb = part + (size_t)(prt * (NB / 4)) * NNODES + n;
        #pragma unroll
        for (int b = 0; b < NB / 4; ++b) {
            unsigned int v = pb[(size_t)b * NNODES];
            int c = (int)(v >> CNT_SHIFT);
            cnt += c;
            sumfix += (int)(v & SUM_MASK) - (c << 19);
        }
    }
    // quad reduce (lanes 4q..4q+3)
    sumfix += __shfl_down(sumfix, 1);
    sumfix += __shfl_down(sumfix, 2);
    cnt    += __shfl_down(cnt, 1);
    cnt    += __shfl_down(cnt, 2);

    if (prt == 0 && n < NNODES) {
        float sacc = (float)sumfix * (1.0f / 65536.0f);
        float cmax = fmaxf((float)cnt, 1.0f);
        float cfac = (cnt > 0) ? 1.0f : 0.0f;
        float logit = xu[n] + cfac * (xp[n] + scal[0]) + sacc / cmax + scal[2];
        float pr = 1.0f / (1.0f + expf(-logit));
        out[n] = (pr > 0.5f) ? 1.0f : 0.0f;
        out[NNODES + n] = pr;
    }
}

extern "C" void kernel_launch(void* const* d_in, const int* in_sizes, int n_in,
                              void* d_out, int out_size, void* d_ws, size_t ws_size,
                              hipStream_t stream) {
    const float* x_a       = (const float*)d_in[0];
    const int*   ei        = (const int*)d_in[1];    // [2, E]
    const float* edge_attr = (const float*)d_in[2];  // [E, 1]
    const float* g_w       = (const float*)d_in[3];  // [257,128]
    const float* g_b       = (const float*)d_in[4];  // [128]
    const float* f_w       = (const float*)d_in[5];  // [256,128]
    const float* f_b       = (const float*)d_in[6];  // [128]
    const float* cls_w     = (const float*)d_in[7];  // [128,1]
    const float* cls_b     = (const float*)d_in[8];  // [1]
    float* out = (float*)d_out;

    // workspace layout: part first (16B-aligned at ws base), then node scalars
    unsigned int* part = (unsigned int*)d_ws;                  // NB*N u32 = 10.24 MB
    float* xu   = (float*)d_ws + (size_t)NB * NNODES;          // N
    float* xp   = xu + NNODES;                                 // N
    float* r    = xp + NNODES;                                 // N
    float* scal = r + NNODES;                                  // 4

    k_node<<<256, BT, 0, stream>>>(x_a, g_w, g_b, f_w, f_b, cls_w, cls_b,
                                   xu, xp, r, scal);

    k_edge<<<NB, BT, 0, stream>>>(ei, edge_attr, r, scal, part);

    k_final<<<(NNODES + 63) / 64, 256, 0, stream>>>(xu, xp, part, scal, out);
}